// Round 4
// baseline (744.345 us; speedup 1.0000x reference)
//
#include <hip/hip_runtime.h>
#include <math.h>

#define K 8192
#define BROWS 4096
#define ALPHA 0.5f

// 16B vector with only-4B alignment guarantee (misaligned load side of the copy)
typedef float f4u __attribute__((ext_vector_type(4), aligned(4)));

__device__ __forceinline__ void argmax_combine(float& v, int& i, float v2, int i2){
  if (v2 > v || (v2 == v && i2 < i)) { v = v2; i = i2; }
}

// One block (256 threads) per row. The 32 KB row is staged in LDS (not
// registers -> no spills; round-3's fused kernel showed VGPR_Count=44, too
// small to hold x[32], so phases serialized on scratch/reload latency).
// Element mapping per thread matches earlier rounds exactly -> identical
// numerics (absmax was 0.0).
__global__ __launch_bounds__(256) void row_stats_kernel(
    const float* __restrict__ outputs,
    const float* __restrict__ targets,
    const float* __restrict__ S,
    float* __restrict__ rowloss,
    int*   __restrict__ rowtl,
    int*   __restrict__ rowcorrect,
    float* __restrict__ rowm,
    float* __restrict__ rowinvZ)
{
  __shared__ float xs[K];                       // 32 KB row stage
  __shared__ float s_v[2][4]; __shared__ int s_i[2][4];
  __shared__ float s_m; __shared__ int s_pred; __shared__ int s_tl;
  __shared__ float s_sums[4][5];

  const int b = blockIdx.x;
  const int t = threadIdx.x;
  const int lane = t & 63;
  const int wid  = t >> 6;   // 0..3
  float4* xs4 = (float4*)xs;

  // ---- phase 1: load row (8 independent float4 loads), stage to LDS, argmax
  const float4* orow = (const float4*)(outputs + (size_t)b * K);
  float4 xv[8];
#pragma unroll
  for (int i = 0; i < 8; ++i) xv[i] = orow[i*256 + t];

  float mv = -INFINITY; int mi = 0x7fffffff;
#pragma unroll
  for (int i = 0; i < 8; ++i){
    xs4[i*256 + t] = xv[i];
    const float xc[4] = {xv[i].x, xv[i].y, xv[i].z, xv[i].w};
#pragma unroll
    for (int c = 0; c < 4; ++c)
      argmax_combine(mv, mi, xc[c], i*1024 + t*4 + c);
  }

  // ---- phase 2: targets (8 independent loads) + hard-CE dots + target argmax
  const float4* trow = (const float4*)(targets + (size_t)b * K);
  float4 tvv[8];
#pragma unroll
  for (int i = 0; i < 8; ++i) tvv[i] = trow[i*256 + t];

  float tv = -INFINITY; int ti = 0x7fffffff;
  float d_hard = 0.f, s_hard = 0.f;
#pragma unroll
  for (int i = 0; i < 8; ++i){
    const float xc[4] = {xv[i].x, xv[i].y, xv[i].z, xv[i].w};
    const float tc[4] = {tvv[i].x, tvv[i].y, tvv[i].z, tvv[i].w};
#pragma unroll
    for (int c = 0; c < 4; ++c){
      d_hard += xc[c] * tc[c];
      s_hard += tc[c];
      argmax_combine(tv, ti, tc[c], i*1024 + t*4 + c);
    }
  }

  // ---- block argmax reductions
#pragma unroll
  for (int off = 32; off; off >>= 1){
    float v2 = __shfl_down(mv, off, 64); int i2 = __shfl_down(mi, off, 64);
    argmax_combine(mv, mi, v2, i2);
    v2 = __shfl_down(tv, off, 64); i2 = __shfl_down(ti, off, 64);
    argmax_combine(tv, ti, v2, i2);
  }
  if (lane == 0){ s_v[0][wid]=mv; s_i[0][wid]=mi; s_v[1][wid]=tv; s_i[1][wid]=ti; }
  __syncthreads();
  if (t == 0){
    float av=s_v[0][0]; int ai=s_i[0][0];
    float bv=s_v[1][0]; int bi=s_i[1][0];
#pragma unroll
    for (int w=1; w<4; ++w){
      argmax_combine(av, ai, s_v[0][w], s_i[0][w]);
      argmax_combine(bv, bi, s_v[1][w], s_i[1][w]);
    }
    s_m = av; s_pred = ai; s_tl = bi;
  }
  __syncthreads();
  const float m  = s_m;
  const int   tl = s_tl;

  // ---- phase 3: S-row gather (8 independent loads) + soft-CE dots + exp sum
  const float4* srow = (const float4*)(S + (size_t)tl * K);
  float4 svv[8];
#pragma unroll
  for (int i = 0; i < 8; ++i) svv[i] = srow[i*256 + t];

  float se = 0.f, d_soft = 0.f, s_soft = 0.f;
#pragma unroll
  for (int i = 0; i < 8; ++i){
    float4 xr = xs4[i*256 + t];                 // row from LDS
    const float xc[4] = {xr.x, xr.y, xr.z, xr.w};
    const float sc[4] = {svv[i].x, svv[i].y, svv[i].z, svv[i].w};
#pragma unroll
    for (int c = 0; c < 4; ++c){
      se     += expf(xc[c] - m);
      d_soft += xc[c] * sc[c];
      s_soft += sc[c];
    }
  }

  // ---- block-reduce the 5 sums
  float sums[5] = {d_hard, s_hard, se, d_soft, s_soft};
#pragma unroll
  for (int off = 32; off; off >>= 1){
#pragma unroll
    for (int j = 0; j < 5; ++j) sums[j] += __shfl_down(sums[j], off, 64);
  }
  if (lane == 0){
#pragma unroll
    for (int j = 0; j < 5; ++j) s_sums[wid][j] = sums[j];
  }
  __syncthreads();
  if (t == 0){
    float tot[5];
#pragma unroll
    for (int j=0;j<5;++j)
      tot[j] = s_sums[0][j]+s_sums[1][j]+s_sums[2][j]+s_sums[3][j];
    float Z = tot[2];
    float logZ = logf(Z);
    // sum(ls * w) = d - (m + logZ) * s   where ls = x - m - logZ
    float ceh = -(tot[0] - (m + logZ) * tot[1]);
    float ces = -(tot[3] - (m + logZ) * tot[4]);
    rowloss[b]    = (ALPHA * ceh + (1.0f - ALPHA) * ces) * (1.0f / (float)BROWS);
    rowtl[b]      = tl;
    rowcorrect[b] = (s_pred == tl) ? 1 : 0;
    rowm[b]       = m;
    rowinvZ[b]    = 1.0f / Z;
  }
}

// S_t (256 MB) -> out_St copy, deep-MLP float4. dst = d_out+1 (4B-aligned);
// dst+3 is 16B-aligned, loads from src+3 are 4B-aligned dwordx4 (OK on gfx950).
// Bulk: n4 = 16777215 float4s; head elems {0,1,2}; tail elem {67108863}.
// Each thread issues 8 independent loads (8 KB/wave in flight) then 8 stores.
__global__ __launch_bounds__(256) void copy_st_kernel(const float* __restrict__ src,
                                                      float* __restrict__ dst){
  const f4u*  s4 = (const f4u*)(src + 3);
  float4*     d4 = (float4*)(dst + 3);
  const size_t n4     = 16777215UL;
  const size_t stride = 2097152UL;              // 8192 blocks x 256 threads
  const size_t i = (size_t)blockIdx.x * 256 + threadIdx.x;

  if (i != stride - 1){
    // full 8 slots: i + 7*stride <= n4-1
    float4 v[8];
#pragma unroll
    for (int k = 0; k < 8; ++k){
      f4u u = s4[i + (size_t)k * stride];
      v[k] = *(const float4*)&u;
    }
#pragma unroll
    for (int k = 0; k < 8; ++k)
      d4[i + (size_t)k * stride] = v[k];
  } else {
    // last thread: 7 slots (i + 7*stride == n4)
    float4 v[7];
#pragma unroll
    for (int k = 0; k < 7; ++k){
      f4u u = s4[i + (size_t)k * stride];
      v[k] = *(const float4*)&u;
    }
#pragma unroll
    for (int k = 0; k < 7; ++k)
      d4[i + (size_t)k * stride] = v[k];
    // head + tail scalars
    dst[0] = src[0]; dst[1] = src[1]; dst[2] = src[2];
    dst[67108863] = src[67108863];
  }
}

// Fused tail: blocks 0..BROWS-1 scatter probs for correct rows (expected ~0-2
// of 4096; early exit otherwise); block BROWS does the deterministic loss
// reduction + count copy.
__global__ __launch_bounds__(256) void tail_kernel(const float* __restrict__ outputs,
    const int* __restrict__ rowtl, const int* __restrict__ rowcorrect,
    const float* __restrict__ rowm, const float* __restrict__ rowinvZ,
    const float* __restrict__ rowloss, const float* __restrict__ count,
    float* __restrict__ out_loss, float* __restrict__ out_St,
    float* __restrict__ out_count){
  const int b = blockIdx.x;
  const int t = threadIdx.x;
  if (b == BROWS){
    float s = 0.f;
    for (int i = t; i < BROWS; i += 256) s += rowloss[i];
#pragma unroll
    for (int off = 32; off; off >>= 1) s += __shfl_down(s, off, 64);
    __shared__ float sh[4];
    if ((t & 63) == 0) sh[t >> 6] = s;
    __syncthreads();
    if (t == 0) out_loss[0] = sh[0] + sh[1] + sh[2] + sh[3];
    for (int i = t; i < K; i += 256) out_count[i] = count[i];
    return;
  }
  if (!rowcorrect[b]) return;
  const int tl = rowtl[b];
  const float m = rowm[b], invZ = rowinvZ[b];
  const float* orow = outputs + (size_t)b * K;
  float* drow = out_St + (size_t)tl * K;
  for (int k = t; k < K; k += 256)
    atomicAdd(&drow[k], expf(orow[k] - m) * invZ);
  if (t == 0) atomicAdd(&out_count[tl], 1.0f);
}

extern "C" void kernel_launch(void* const* d_in, const int* in_sizes, int n_in,
                              void* d_out, int out_size, void* d_ws, size_t ws_size,
                              hipStream_t stream) {
  const float* outputs = (const float*)d_in[0];
  const float* targets = (const float*)d_in[1];
  const float* S       = (const float*)d_in[2];
  const float* S_t     = (const float*)d_in[3];
  const float* count   = (const float*)d_in[4];

  float* out       = (float*)d_out;
  float* out_loss  = out;
  float* out_St    = out + 1;
  float* out_count = out + 1 + (size_t)K * K;

  float* rowloss    = (float*)d_ws;            // B floats
  float* rowm       = rowloss + BROWS;         // B floats
  float* rowinvZ    = rowm + BROWS;            // B floats
  int*   rowtl      = (int*)(rowinvZ + BROWS); // B ints
  int*   rowcorrect = rowtl + BROWS;           // B ints

  hipLaunchKernelGGL(row_stats_kernel, dim3(BROWS), dim3(256), 0, stream,
                     outputs, targets, S, rowloss, rowtl, rowcorrect, rowm, rowinvZ);
  hipLaunchKernelGGL(copy_st_kernel, dim3(8192), dim3(256), 0, stream, S_t, out_St);
  hipLaunchKernelGGL(tail_kernel, dim3(BROWS + 1), dim3(256), 0, stream,
                     outputs, rowtl, rowcorrect, rowm, rowinvZ, rowloss, count,
                     out_loss, out_St, out_count);
}

// Round 5
// 733.935 us; speedup vs baseline: 1.0142x; 1.0142x over previous
//
#include <hip/hip_runtime.h>
#include <math.h>

#define K 8192
#define BROWS 4096
#define ALPHA 0.5f

// 16B vector with only-4B alignment guarantee (misaligned load side of the copy)
typedef float f4u __attribute__((ext_vector_type(4), aligned(4)));

__device__ __forceinline__ void argmax_combine(float& v, int& i, float v2, int i2){
  if (v2 > v || (v2 == v && i2 < i)) { v = v2; i = i2; }
}

// Fused kernel: 12288 blocks x 256 threads.
//   bb % 3 == 0 -> row_stats for row bb/3           (4096 row blocks)
//   else        -> S_t copy slice (bb/3)*2 + (bb%3-1) (8192 copy slices)
// R3 showed fusion alone is latency-bound (2.66 TB/s) because the row path
// spilled (VGPR_Count=44 with x[32] live). This version stages the row in LDS
// (R4's row kernel) so neither path spills, while copy blocks stay co-resident
// to fill the row path's barrier/latency bubbles. launch_bounds(256,4):
// <=128 VGPR/wave; LDS (32KB) caps residency at 4 blocks/CU = 16 waves/CU.
__global__ __launch_bounds__(256, 4) void fused_kernel(
    const float* __restrict__ outputs,
    const float* __restrict__ targets,
    const float* __restrict__ S,
    const float* __restrict__ S_t,
    float* __restrict__ out_St,
    float* __restrict__ rowloss,
    int*   __restrict__ rowtl,
    int*   __restrict__ rowcorrect,
    float* __restrict__ rowm,
    float* __restrict__ rowinvZ)
{
  __shared__ float xs[K];                       // 32 KB row stage (row path only)
  __shared__ float s_v[2][4]; __shared__ int s_i[2][4];
  __shared__ float s_m; __shared__ int s_pred; __shared__ int s_tl;
  __shared__ float s_sums[4][5];

  const int bb = blockIdx.x;
  const int t  = threadIdx.x;
  const int r  = bb % 3;

  if (r != 0){
    // ---- copy path: 32 KB contiguous slice, deep float4.
    // dst = out_St = d_out+1 (4B-aligned); dst+3 is 16B-aligned, loads from
    // src+3 are 4B-aligned dwordx4 (OK on gfx950).
    // Bulk: n4 = 16777215 float4s over elements [3, 67108862]; head {0,1,2};
    // tail {67108863}. Block c covers float4s [c*2048, c*2048+2047].
    const int c = (bb / 3) * 2 + (r - 1);       // 0..8191
    const f4u* s4 = (const f4u*)(S_t + 3);
    float4*    d4 = (float4*)(out_St + 3);
    const size_t base = (size_t)c * 2048 + t;
    if (c != 8191){
      float4 v[8];
#pragma unroll
      for (int k = 0; k < 8; ++k){
        f4u u = s4[base + (size_t)k * 256];
        v[k] = *(const float4*)&u;
      }
#pragma unroll
      for (int k = 0; k < 8; ++k)
        d4[base + (size_t)k * 256] = v[k];
    } else {
      // last block: top float4 index would be 16777215 == n4 -> guard it
#pragma unroll
      for (int k = 0; k < 8; ++k){
        size_t idx = base + (size_t)k * 256;
        if (idx < 16777215UL){
          f4u u = s4[idx];
          d4[idx] = *(const float4*)&u;
        }
      }
      if (t == 255){
        out_St[0] = S_t[0]; out_St[1] = S_t[1]; out_St[2] = S_t[2];
        out_St[67108863] = S_t[67108863];
      }
    }
    return;
  }

  // ---- row path ----
  const int b = bb / 3;
  const int lane = t & 63;
  const int wid  = t >> 6;   // 0..3
  float4* xs4 = (float4*)xs;

  // phase 1: load row (8 independent float4 loads), stage to LDS, argmax
  const float4* orow = (const float4*)(outputs + (size_t)b * K);
  float4 xv[8];
#pragma unroll
  for (int i = 0; i < 8; ++i) xv[i] = orow[i*256 + t];

  float mv = -INFINITY; int mi = 0x7fffffff;
#pragma unroll
  for (int i = 0; i < 8; ++i){
    xs4[i*256 + t] = xv[i];
    const float xc[4] = {xv[i].x, xv[i].y, xv[i].z, xv[i].w};
#pragma unroll
    for (int c = 0; c < 4; ++c)
      argmax_combine(mv, mi, xc[c], i*1024 + t*4 + c);
  }

  // phase 2: targets (8 independent loads) + hard-CE dots + target argmax
  const float4* trow = (const float4*)(targets + (size_t)b * K);
  float4 tvv[8];
#pragma unroll
  for (int i = 0; i < 8; ++i) tvv[i] = trow[i*256 + t];

  float tv = -INFINITY; int ti = 0x7fffffff;
  float d_hard = 0.f, s_hard = 0.f;
#pragma unroll
  for (int i = 0; i < 8; ++i){
    const float xc[4] = {xv[i].x, xv[i].y, xv[i].z, xv[i].w};
    const float tc[4] = {tvv[i].x, tvv[i].y, tvv[i].z, tvv[i].w};
#pragma unroll
    for (int c = 0; c < 4; ++c){
      d_hard += xc[c] * tc[c];
      s_hard += tc[c];
      argmax_combine(tv, ti, tc[c], i*1024 + t*4 + c);
    }
  }

  // block argmax reductions
#pragma unroll
  for (int off = 32; off; off >>= 1){
    float v2 = __shfl_down(mv, off, 64); int i2 = __shfl_down(mi, off, 64);
    argmax_combine(mv, mi, v2, i2);
    v2 = __shfl_down(tv, off, 64); i2 = __shfl_down(ti, off, 64);
    argmax_combine(tv, ti, v2, i2);
  }
  if (lane == 0){ s_v[0][wid]=mv; s_i[0][wid]=mi; s_v[1][wid]=tv; s_i[1][wid]=ti; }
  __syncthreads();
  if (t == 0){
    float av=s_v[0][0]; int ai=s_i[0][0];
    float bv=s_v[1][0]; int bi=s_i[1][0];
#pragma unroll
    for (int w=1; w<4; ++w){
      argmax_combine(av, ai, s_v[0][w], s_i[0][w]);
      argmax_combine(bv, bi, s_v[1][w], s_i[1][w]);
    }
    s_m = av; s_pred = ai; s_tl = bi;
  }
  __syncthreads();
  const float m  = s_m;
  const int   tl = s_tl;

  // phase 3: S-row gather (8 independent loads) + soft-CE dots + exp sum
  const float4* srow = (const float4*)(S + (size_t)tl * K);
  float4 svv[8];
#pragma unroll
  for (int i = 0; i < 8; ++i) svv[i] = srow[i*256 + t];

  float se = 0.f, d_soft = 0.f, s_soft = 0.f;
#pragma unroll
  for (int i = 0; i < 8; ++i){
    float4 xr = xs4[i*256 + t];                 // row from LDS
    const float xc[4] = {xr.x, xr.y, xr.z, xr.w};
    const float sc[4] = {svv[i].x, svv[i].y, svv[i].z, svv[i].w};
#pragma unroll
    for (int c = 0; c < 4; ++c){
      se     += expf(xc[c] - m);
      d_soft += xc[c] * sc[c];
      s_soft += sc[c];
    }
  }

  // block-reduce the 5 sums
  float sums[5] = {d_hard, s_hard, se, d_soft, s_soft};
#pragma unroll
  for (int off = 32; off; off >>= 1){
#pragma unroll
    for (int j = 0; j < 5; ++j) sums[j] += __shfl_down(sums[j], off, 64);
  }
  if (lane == 0){
#pragma unroll
    for (int j = 0; j < 5; ++j) s_sums[wid][j] = sums[j];
  }
  __syncthreads();
  if (t == 0){
    float tot[5];
#pragma unroll
    for (int j=0;j<5;++j)
      tot[j] = s_sums[0][j]+s_sums[1][j]+s_sums[2][j]+s_sums[3][j];
    float Z = tot[2];
    float logZ = logf(Z);
    // sum(ls * w) = d - (m + logZ) * s   where ls = x - m - logZ
    float ceh = -(tot[0] - (m + logZ) * tot[1]);
    float ces = -(tot[3] - (m + logZ) * tot[4]);
    rowloss[b]    = (ALPHA * ceh + (1.0f - ALPHA) * ces) * (1.0f / (float)BROWS);
    rowtl[b]      = tl;
    rowcorrect[b] = (s_pred == tl) ? 1 : 0;
    rowm[b]       = m;
    rowinvZ[b]    = 1.0f / Z;
  }
}

// Fused tail: blocks 0..BROWS-1 scatter probs for correct rows (expected ~0-2
// of 4096; early exit otherwise); block BROWS does the deterministic loss
// reduction + count copy.
__global__ __launch_bounds__(256) void tail_kernel(const float* __restrict__ outputs,
    const int* __restrict__ rowtl, const int* __restrict__ rowcorrect,
    const float* __restrict__ rowm, const float* __restrict__ rowinvZ,
    const float* __restrict__ rowloss, const float* __restrict__ count,
    float* __restrict__ out_loss, float* __restrict__ out_St,
    float* __restrict__ out_count){
  const int b = blockIdx.x;
  const int t = threadIdx.x;
  if (b == BROWS){
    float s = 0.f;
    for (int i = t; i < BROWS; i += 256) s += rowloss[i];
#pragma unroll
    for (int off = 32; off; off >>= 1) s += __shfl_down(s, off, 64);
    __shared__ float sh[4];
    if ((t & 63) == 0) sh[t >> 6] = s;
    __syncthreads();
    if (t == 0) out_loss[0] = sh[0] + sh[1] + sh[2] + sh[3];
    for (int i = t; i < K; i += 256) out_count[i] = count[i];
    return;
  }
  if (!rowcorrect[b]) return;
  const int tl = rowtl[b];
  const float m = rowm[b], invZ = rowinvZ[b];
  const float* orow = outputs + (size_t)b * K;
  float* drow = out_St + (size_t)tl * K;
  for (int k = t; k < K; k += 256)
    atomicAdd(&drow[k], expf(orow[k] - m) * invZ);
  if (t == 0) atomicAdd(&out_count[tl], 1.0f);
}

extern "C" void kernel_launch(void* const* d_in, const int* in_sizes, int n_in,
                              void* d_out, int out_size, void* d_ws, size_t ws_size,
                              hipStream_t stream) {
  const float* outputs = (const float*)d_in[0];
  const float* targets = (const float*)d_in[1];
  const float* S       = (const float*)d_in[2];
  const float* S_t     = (const float*)d_in[3];
  const float* count   = (const float*)d_in[4];

  float* out       = (float*)d_out;
  float* out_loss  = out;
  float* out_St    = out + 1;
  float* out_count = out + 1 + (size_t)K * K;

  float* rowloss    = (float*)d_ws;            // B floats
  float* rowm       = rowloss + BROWS;         // B floats
  float* rowinvZ    = rowm + BROWS;            // B floats
  int*   rowtl      = (int*)(rowinvZ + BROWS); // B ints
  int*   rowcorrect = rowtl + BROWS;           // B ints

  hipLaunchKernelGGL(fused_kernel, dim3(3 * BROWS), dim3(256), 0, stream,
                     outputs, targets, S, S_t, out_St,
                     rowloss, rowtl, rowcorrect, rowm, rowinvZ);
  hipLaunchKernelGGL(tail_kernel, dim3(BROWS + 1), dim3(256), 0, stream,
                     outputs, rowtl, rowcorrect, rowm, rowinvZ, rowloss, count,
                     out_loss, out_St, out_count);
}